// Round 7
// baseline (178.319 us; speedup 1.0000x reference)
//
#include <hip/hip_runtime.h>

#define DIOU_EPS 1e-7f

constexpr int BLOCK = 256;              // 4 waves
constexpr int VPT   = 4;                // consecutive elements per thread
constexpr int TILE  = BLOCK * VPT;      // 1024 elements per block, one tile per block

__global__ void zero_out_kernel(float* out) {
    out[0] = 0.0f;                      // d_out is re-poisoned 0xAA before every replay
}

__device__ __forceinline__ float rcp_fast(float x) {
    return __builtin_amdgcn_rcpf(x);    // v_rcp_f32 ~1ulp; abs threshold 3.8e-2 -> safe
}

__device__ __forceinline__ float diou_elem(float4 a, float4 b, int m) {
    float a1 = (a.z - a.x) * (a.w - a.y);
    float a2 = (b.z - b.x) * (b.w - b.y);

    float iw = fmaxf(fminf(a.z, b.z) - fmaxf(a.x, b.x), 0.0f);
    float ih = fmaxf(fminf(a.w, b.w) - fmaxf(a.y, b.y), 0.0f);
    float inter = iw * ih;
    float uni = a1 + a2 - inter;

    float wc = fmaxf(a.z, b.z) - fminf(a.x, b.x);
    float hc = fmaxf(a.w, b.w) - fminf(a.y, b.y);
    float area_c = wc * hc;

    float dx = (a.x + a.z - b.x - b.z) * 0.5f;
    float dy = (a.y + a.w - b.y - b.w) * 0.5f;
    float d2 = dx * dx + dy * dy;
    float diag2 = wc * wc + hc * hc;

    // loss = 1 - diou = 2 - inter/uni - uni/area_c + d2/(diag2+eps)
    float loss = 2.0f - inter * rcp_fast(uni)
                      - uni   * rcp_fast(area_c)
                      + d2    * rcp_fast(diag2 + DIOU_EPS);

    return (m != 0) ? loss : 0.0f;
}

// One tile per block (R6 structure, best-of-six). Block partial goes straight to
// out[0] via one device-scope atomicAdd per block — finalize kernel eliminated.
__global__ __launch_bounds__(BLOCK, 8) void diou_loss_kernel(
    const float4* __restrict__ boxes1,
    const float4* __restrict__ boxes2,
    const int* __restrict__ mask,
    const int* __restrict__ num_boxes,
    float* __restrict__ out,
    int n)
{
    const int t = threadIdx.x;
    const long long base = (long long)blockIdx.x * TILE;
    float acc = 0.0f;

    if (base + TILE <= n) {
        const long long e0 = base + (long long)t * VPT;
        float4 A[VPT], B[VPT];
        #pragma unroll
        for (int j = 0; j < VPT; ++j) A[j] = boxes1[e0 + j];
        #pragma unroll
        for (int j = 0; j < VPT; ++j) B[j] = boxes2[e0 + j];
        int4 M4 = ((const int4*)mask)[e0 >> 2];

        __builtin_amdgcn_sched_barrier(0);   // 9 loads issued before compute

        int mm[VPT] = {M4.x, M4.y, M4.z, M4.w};
        #pragma unroll
        for (int j = 0; j < VPT; ++j) acc += diou_elem(A[j], B[j], mm[j]);
    } else {
        // tail (unused for n = 4,194,304)
        for (int j = 0; j < VPT; ++j) {
            long long i = base + (long long)t * VPT + j;
            if (i < n) acc += diou_elem(boxes1[i], boxes2[i], mask[i]);
        }
    }

    // block reduce
    #pragma unroll
    for (int off = 32; off > 0; off >>= 1)
        acc += __shfl_down(acc, off, 64);

    __shared__ float wsum[BLOCK / 64];
    if ((t & 63) == 0) wsum[t >> 6] = acc;
    __syncthreads();

    if (t == 0) {
        float s = wsum[0] + wsum[1] + wsum[2] + wsum[3];
        atomicAdd(out, s * rcp_fast((float)num_boxes[0]) *
                           (float)num_boxes[0] / (float)num_boxes[0]);
        // NOTE: expression above intentionally simplified below — see launch
    }
}

// Correct, simple version of the tail (replaces the over-clever line above).
__global__ __launch_bounds__(BLOCK, 8) void diou_loss_kernel_v2(
    const float4* __restrict__ boxes1,
    const float4* __restrict__ boxes2,
    const int* __restrict__ mask,
    const int* __restrict__ num_boxes,
    float* __restrict__ out,
    int n)
{
    const int t = threadIdx.x;
    const long long base = (long long)blockIdx.x * TILE;
    float acc = 0.0f;

    if (base + TILE <= n) {
        const long long e0 = base + (long long)t * VPT;
        float4 A[VPT], B[VPT];
        #pragma unroll
        for (int j = 0; j < VPT; ++j) A[j] = boxes1[e0 + j];
        #pragma unroll
        for (int j = 0; j < VPT; ++j) B[j] = boxes2[e0 + j];
        int4 M4 = ((const int4*)mask)[e0 >> 2];

        __builtin_amdgcn_sched_barrier(0);

        int mm[VPT] = {M4.x, M4.y, M4.z, M4.w};
        #pragma unroll
        for (int j = 0; j < VPT; ++j) acc += diou_elem(A[j], B[j], mm[j]);
    } else {
        for (int j = 0; j < VPT; ++j) {
            long long i = base + (long long)t * VPT + j;
            if (i < n) acc += diou_elem(boxes1[i], boxes2[i], mask[i]);
        }
    }

    #pragma unroll
    for (int off = 32; off > 0; off >>= 1)
        acc += __shfl_down(acc, off, 64);

    __shared__ float wsum[BLOCK / 64];
    if ((t & 63) == 0) wsum[t >> 6] = acc;
    __syncthreads();

    if (t == 0) {
        float s = (wsum[0] + wsum[1] + wsum[2] + wsum[3]) / (float)num_boxes[0];
        atomicAdd(out, s);
    }
}

extern "C" void kernel_launch(void* const* d_in, const int* in_sizes, int n_in,
                              void* d_out, int out_size, void* d_ws, size_t ws_size,
                              hipStream_t stream) {
    const float4* boxes1 = (const float4*)d_in[0];   // (B,Q,4) f32
    const float4* boxes2 = (const float4*)d_in[1];   // (B,Q,4) f32
    const int* mask = (const int*)d_in[2];           // (B,Q) bool -> int32
    const int* num_boxes = (const int*)d_in[3];      // scalar

    float* out = (float*)d_out;
    int n = in_sizes[2];                             // B*Q pairs

    zero_out_kernel<<<1, 1, 0, stream>>>(out);

    int grid = (n + TILE - 1) / TILE;                // 4096
    diou_loss_kernel_v2<<<grid, BLOCK, 0, stream>>>(boxes1, boxes2, mask,
                                                    num_boxes, out, n);
}

// Round 8
// 164.158 us; speedup vs baseline: 1.0863x; 1.0863x over previous
//
#include <hip/hip_runtime.h>

#define DIOU_EPS 1e-7f

constexpr int BLOCK = 256;              // 4 waves
constexpr int VPT   = 4;                // consecutive elements per thread
constexpr int TILE  = BLOCK * VPT;      // 1024 elements per block, one tile per block

__device__ __forceinline__ float rcp_fast(float x) {
    return __builtin_amdgcn_rcpf(x);    // v_rcp_f32 ~1ulp; abs threshold 3.8e-2 -> safe
}

__device__ __forceinline__ float diou_elem(float4 a, float4 b, int m) {
    float a1 = (a.z - a.x) * (a.w - a.y);
    float a2 = (b.z - b.x) * (b.w - b.y);

    float iw = fmaxf(fminf(a.z, b.z) - fmaxf(a.x, b.x), 0.0f);
    float ih = fmaxf(fminf(a.w, b.w) - fmaxf(a.y, b.y), 0.0f);
    float inter = iw * ih;
    float uni = a1 + a2 - inter;

    float wc = fmaxf(a.z, b.z) - fminf(a.x, b.x);
    float hc = fmaxf(a.w, b.w) - fminf(a.y, b.y);
    float area_c = wc * hc;

    float dx = (a.x + a.z - b.x - b.z) * 0.5f;
    float dy = (a.y + a.w - b.y - b.w) * 0.5f;
    float d2 = dx * dx + dy * dy;
    float diag2 = wc * wc + hc * hc;

    // loss = 1 - diou = 2 - inter/uni - uni/area_c + d2/(diag2+eps)
    float loss = 2.0f - inter * rcp_fast(uni)
                      - uni   * rcp_fast(area_c)
                      + d2    * rcp_fast(diag2 + DIOU_EPS);

    return (m != 0) ? loss : 0.0f;
}

// R6 structure (best of seven rounds): one 1024-elem tile per block, no loop,
// full occupancy (__launch_bounds__(256,8), 32 VGPR -> 8 waves/SIMD), 9 loads
// per thread pinned ahead of compute, per-block partial to d_ws (NO atomics —
// the single-address atomicAdd variant cost +14 us in R7).
__global__ __launch_bounds__(BLOCK, 8) void diou_partial_kernel(
    const float4* __restrict__ boxes1,
    const float4* __restrict__ boxes2,
    const int* __restrict__ mask,
    float* __restrict__ ws,
    int n)
{
    const int t = threadIdx.x;
    const long long base = (long long)blockIdx.x * TILE;
    float acc = 0.0f;

    if (base + TILE <= n) {
        const long long e0 = base + (long long)t * VPT;
        float4 A[VPT], B[VPT];
        #pragma unroll
        for (int j = 0; j < VPT; ++j) A[j] = boxes1[e0 + j];
        #pragma unroll
        for (int j = 0; j < VPT; ++j) B[j] = boxes2[e0 + j];
        int4 M4 = ((const int4*)mask)[e0 >> 2];

        __builtin_amdgcn_sched_barrier(0);   // all 9 loads issued before compute

        int mm[VPT] = {M4.x, M4.y, M4.z, M4.w};
        #pragma unroll
        for (int j = 0; j < VPT; ++j) acc += diou_elem(A[j], B[j], mm[j]);
    } else {
        // tail (unused for n = 4,194,304)
        for (int j = 0; j < VPT; ++j) {
            long long i = base + (long long)t * VPT + j;
            if (i < n) acc += diou_elem(boxes1[i], boxes2[i], mask[i]);
        }
    }

    // block reduce -> one partial per block
    #pragma unroll
    for (int off = 32; off > 0; off >>= 1)
        acc += __shfl_down(acc, off, 64);

    __shared__ float wsum[BLOCK / 64];
    if ((t & 63) == 0) wsum[t >> 6] = acc;
    __syncthreads();
    if (t == 0) ws[blockIdx.x] = wsum[0] + wsum[1] + wsum[2] + wsum[3];
}

__global__ __launch_bounds__(BLOCK) void finalize_kernel(
    const float* __restrict__ ws,
    const int* __restrict__ num_boxes,
    float* __restrict__ out,
    int nblocks)
{
    const int t = threadIdx.x;
    float a = 0.0f;
    for (int i = t; i < nblocks; i += BLOCK) a += ws[i];

    #pragma unroll
    for (int off = 32; off > 0; off >>= 1)
        a += __shfl_down(a, off, 64);

    __shared__ float wsum[BLOCK / 64];
    if ((t & 63) == 0) wsum[t >> 6] = a;
    __syncthreads();
    if (t == 0)
        out[0] = (wsum[0] + wsum[1] + wsum[2] + wsum[3]) / (float)num_boxes[0];
}

extern "C" void kernel_launch(void* const* d_in, const int* in_sizes, int n_in,
                              void* d_out, int out_size, void* d_ws, size_t ws_size,
                              hipStream_t stream) {
    const float4* boxes1 = (const float4*)d_in[0];   // (B,Q,4) f32
    const float4* boxes2 = (const float4*)d_in[1];   // (B,Q,4) f32
    const int* mask = (const int*)d_in[2];           // (B,Q) bool -> int32
    const int* num_boxes = (const int*)d_in[3];      // scalar

    float* out = (float*)d_out;
    float* partials = (float*)d_ws;
    int n = in_sizes[2];                             // B*Q pairs

    int grid = (n + TILE - 1) / TILE;                // 4096: exact cover, every ws slot written
    diou_partial_kernel<<<grid, BLOCK, 0, stream>>>(boxes1, boxes2, mask, partials, n);
    finalize_kernel<<<1, BLOCK, 0, stream>>>(partials, num_boxes, out, grid);
}